// Round 1
// baseline (5986.498 us; speedup 1.0000x reference)
//
#include <hip/hip_runtime.h>
#include <math.h>

#define N_NODES 50000
#define N_EDGES 800000
#define NFEAT 256
#define HID 64
#define NCLS 40
#define EPS_RES 0.3f

// ---------------- degree / normalization ----------------
__global__ void degree_kernel(const int* __restrict__ row, const int* __restrict__ col,
                              int* __restrict__ degi, int* __restrict__ cnti) {
    int e = blockIdx.x * 256 + threadIdx.x;
    atomicAdd(&degi[row[e]], 1);
    atomicAdd(&cnti[col[e]], 1);
}

__global__ void nd_kernel(const int* __restrict__ degi, const int* __restrict__ cnti,
                          float* __restrict__ nd, float* __restrict__ invcnt) {
    int n = blockIdx.x * 256 + threadIdx.x;
    if (n < N_NODES) {
        int d = degi[n]; if (d < 1) d = 1;
        nd[n] = rsqrtf((float)d);
        int c = cnti[n]; if (c < 1) c = 1;
        invcnt[n] = 1.0f / (float)c;
    }
}

// ---------------- input projection: h = relu(x @ W1^T + b1) ----------------
// block = 256 threads = 4 nodes x 64 hid. x rows staged in LDS; W1 streamed (L2-resident).
__global__ void proj_kernel(const float* __restrict__ x, const float* __restrict__ W1,
                            const float* __restrict__ b1, float* __restrict__ h,
                            float* __restrict__ raw) {
    __shared__ float xs[4 * NFEAT];
    int t = threadIdx.x;
    int nb = blockIdx.x * 4;
    const float4* xg = (const float4*)(x + (size_t)nb * NFEAT);
    ((float4*)xs)[t] = xg[t];
    __syncthreads();
    int node = t >> 6, hid = t & 63;
    const float4* w4 = (const float4*)(W1 + hid * NFEAT);
    const float4* xv4 = (const float4*)(xs + node * NFEAT);
    float4 acc = make_float4(0.f, 0.f, 0.f, 0.f);
#pragma unroll
    for (int i = 0; i < NFEAT / 4; i++) {
        float4 w = w4[i];
        float4 xv = xv4[i];
        acc.x += w.x * xv.x;
        acc.y += w.y * xv.y;
        acc.z += w.z * xv.z;
        acc.w += w.w * xv.w;
    }
    float s = (acc.x + acc.y) + (acc.z + acc.w) + b1[hid];
    s = fmaxf(s, 0.f);
    int o = (nb + node) * HID + hid;
    h[o] = s;
    raw[o] = s;
}

// ---------------- per-edge gated message + scatter-add ----------------
__global__ void edge_kernel(const float* __restrict__ h, const int* __restrict__ row,
                            const int* __restrict__ col, const float* __restrict__ nd,
                            const float* __restrict__ gw, const float* __restrict__ gb,
                            float* __restrict__ agg) {
    __shared__ float wab[2 * HID];
    int t = threadIdx.x;
    if (t < 2 * HID) wab[t] = gw[t];
    __syncthreads();
    int e = blockIdx.x * 256 + t;
    int r = row[e], c = col[e];
    const float4* hr4 = (const float4*)(h + r * HID);
    const float4* hc4 = (const float4*)(h + c * HID);
    float da = 0.f, db = 0.f;
#pragma unroll
    for (int i = 0; i < HID / 4; i++) {
        float4 a = hr4[i], b = hc4[i];
        da += a.x * wab[4 * i + 0] + a.y * wab[4 * i + 1] + a.z * wab[4 * i + 2] + a.w * wab[4 * i + 3];
        db += b.x * wab[HID + 4 * i + 0] + b.y * wab[HID + 4 * i + 1] + b.z * wab[HID + 4 * i + 2] + b.w * wab[HID + 4 * i + 3];
    }
    float g = tanhf(da + db + gb[0]);
    float norm = g * nd[r] * nd[c];
    float* aggc = agg + c * HID;
#pragma unroll
    for (int i = 0; i < HID / 4; i++) {
        float4 a = hr4[i], b = hc4[i];
        unsafeAtomicAdd(&aggc[4 * i + 0], norm * (a.x + b.x));
        unsafeAtomicAdd(&aggc[4 * i + 1], norm * (a.y + b.y));
        unsafeAtomicAdd(&aggc[4 * i + 2], norm * (a.z + b.z));
        unsafeAtomicAdd(&aggc[4 * i + 3], norm * (a.w + b.w));
    }
}

// ---------------- h = EPS*raw + agg/cnt ----------------
__global__ void update_kernel(const float* __restrict__ raw, const float* __restrict__ agg,
                              const float* __restrict__ invcnt, float* __restrict__ h) {
    int idx = blockIdx.x * 256 + threadIdx.x;
    int n = idx >> 6;
    h[idx] = EPS_RES * raw[idx] + agg[idx] * invcnt[n];
}

// ---------------- logits + log_softmax ----------------
// block = 256 = 4 waves; one node per wave; lanes 0..39 hold classes.
__global__ void out_kernel(const float* __restrict__ h, const float* __restrict__ W2,
                           const float* __restrict__ b2, float* __restrict__ out) {
    __shared__ float w2s[NCLS * 65];
    __shared__ float b2s[NCLS];
    int t = threadIdx.x;
    for (int i = t; i < NCLS * HID; i += 256) {
        int j = i >> 6, k = i & 63;
        w2s[j * 65 + k] = W2[i];
    }
    if (t < NCLS) b2s[t] = b2[t];
    __syncthreads();
    int node = blockIdx.x * 4 + (t >> 6);
    int lane = t & 63;
    const float* hrow = h + node * HID;
    float logit = 0.f;
    if (lane < NCLS) {
        const float* wr = w2s + lane * 65;
#pragma unroll
        for (int k = 0; k < HID; k++) logit += hrow[k] * wr[k];
        logit += b2s[lane];
    }
    float v = (lane < NCLS) ? logit : -INFINITY;
#pragma unroll
    for (int s = 1; s < 64; s <<= 1) v = fmaxf(v, __shfl_xor(v, s));
    float ex = (lane < NCLS) ? expf(logit - v) : 0.f;
#pragma unroll
    for (int s = 1; s < 64; s <<= 1) ex += __shfl_xor(ex, s);
    float ls = v + logf(ex);
    if (lane < NCLS) out[node * NCLS + lane] = logit - ls;
}

extern "C" void kernel_launch(void* const* d_in, const int* in_sizes, int n_in,
                              void* d_out, int out_size, void* d_ws, size_t ws_size,
                              hipStream_t stream) {
    const float* x  = (const float*)d_in[0];
    const int*   ei = (const int*)d_in[1];   // int32 (JAX x64 disabled)
    const float* W1 = (const float*)d_in[2];
    const float* b1 = (const float*)d_in[3];
    const float* W2 = (const float*)d_in[4];
    const float* b2 = (const float*)d_in[5];
    const float* gw = (const float*)d_in[6];
    const float* gb = (const float*)d_in[7];
    float* out = (float*)d_out;

    // workspace layout (floats): [agg N*H][degi N][cnti N][nd N][invcnt N][h N*H][raw N*H]
    float* ws     = (float*)d_ws;
    float* agg    = ws;
    int*   degi   = (int*)(ws + (size_t)N_NODES * HID);
    int*   cnti   = degi + N_NODES;
    float* nd     = (float*)(cnti + N_NODES);
    float* invcnt = nd + N_NODES;
    float* h      = invcnt + N_NODES;
    float* raw    = h + (size_t)N_NODES * HID;

    const int* row = ei;
    const int* col = ei + N_EDGES;

    // zero agg + degi + cnti in one shot (ws is poisoned 0xAA before every call)
    hipMemsetAsync(agg, 0, ((size_t)N_NODES * HID + 2 * N_NODES) * sizeof(float), stream);

    degree_kernel<<<N_EDGES / 256, 256, 0, stream>>>(row, col, degi, cnti);
    nd_kernel<<<(N_NODES + 255) / 256, 256, 0, stream>>>(degi, cnti, nd, invcnt);
    proj_kernel<<<N_NODES / 4, 256, 0, stream>>>(x, W1, b1, h, raw);

    for (int l = 0; l < 2; l++) {
        if (l) hipMemsetAsync(agg, 0, (size_t)N_NODES * HID * sizeof(float), stream);
        edge_kernel<<<N_EDGES / 256, 256, 0, stream>>>(h, row, col, nd, gw + l * 2 * HID, gb + l, agg);
        update_kernel<<<N_NODES * HID / 256, 256, 0, stream>>>(raw, agg, invcnt, h);
    }

    out_kernel<<<N_NODES / 4, 256, 0, stream>>>(h, W2, b2, out);
}

// Round 2
// 896.492 us; speedup vs baseline: 6.6777x; 6.6777x over previous
//
#include <hip/hip_runtime.h>
#include <math.h>

#define N_NODES 50000
#define N_EDGES 800000
#define NFEAT 256
#define HID 64
#define NCLS 40
#define EPS_RES 0.3f

// ---------------- degree / normalization ----------------
__global__ void degree_kernel(const int* __restrict__ row, const int* __restrict__ col,
                              int* __restrict__ degi, int* __restrict__ cnti) {
    int e = blockIdx.x * 256 + threadIdx.x;
    atomicAdd(&degi[row[e]], 1);
    atomicAdd(&cnti[col[e]], 1);
}

__global__ void nd_kernel(const int* __restrict__ degi, const int* __restrict__ cnti,
                          float* __restrict__ nd, float* __restrict__ invcnt) {
    int n = blockIdx.x * 256 + threadIdx.x;
    if (n < N_NODES) {
        int d = degi[n]; if (d < 1) d = 1;
        nd[n] = rsqrtf((float)d);
        int c = cnti[n]; if (c < 1) c = 1;
        invcnt[n] = 1.0f / (float)c;
    }
}

// ---------------- exclusive prefix sum of cnti -> off (single block) ----------------
__global__ void scan_kernel(const int* __restrict__ cnti, int* __restrict__ off) {
    __shared__ int part[1024];
    int t = threadIdx.x;
    const int CH = (N_NODES + 1023) / 1024;  // 49 elements per thread
    int base = t * CH;
    int s = 0;
    for (int i = 0; i < CH; i++) { int idx = base + i; if (idx < N_NODES) s += cnti[idx]; }
    part[t] = s;
    __syncthreads();
    for (int d = 1; d < 1024; d <<= 1) {
        int v = (t >= d) ? part[t - d] : 0;
        __syncthreads();
        part[t] += v;
        __syncthreads();
    }
    int excl = part[t] - s;  // exclusive prefix for this thread's chunk
    for (int i = 0; i < CH; i++) {
        int idx = base + i;
        if (idx < N_NODES) { off[idx] = excl; excl += cnti[idx]; }
    }
    if (t == 0) off[N_NODES] = N_EDGES;
}

// ---------------- counting-sort scatter: edges grouped by target (CSR) ----------------
__global__ void scatter_kernel(const int* __restrict__ row, const int* __restrict__ col,
                               const float* __restrict__ nd, const int* __restrict__ off,
                               int* __restrict__ fill, int* __restrict__ srow,
                               float* __restrict__ snde) {
    int e = blockIdx.x * 256 + threadIdx.x;
    int r = row[e], c = col[e];
    int p = off[c] + atomicAdd(&fill[c], 1);
    srow[p] = r;
    snde[p] = nd[r] * nd[c];
}

// ---------------- input projection: ha = relu(x @ W1^T + b1) ----------------
__global__ void proj_kernel(const float* __restrict__ x, const float* __restrict__ W1,
                            const float* __restrict__ b1, float* __restrict__ ha) {
    __shared__ float xs[4 * NFEAT];
    int t = threadIdx.x;
    int nb = blockIdx.x * 4;
    const float4* xg = (const float4*)(x + (size_t)nb * NFEAT);
    ((float4*)xs)[t] = xg[t];
    __syncthreads();
    int node = t >> 6, hid = t & 63;
    const float4* w4 = (const float4*)(W1 + hid * NFEAT);
    const float4* xv4 = (const float4*)(xs + node * NFEAT);
    float4 acc = make_float4(0.f, 0.f, 0.f, 0.f);
#pragma unroll
    for (int i = 0; i < NFEAT / 4; i++) {
        float4 w = w4[i];
        float4 xv = xv4[i];
        acc.x += w.x * xv.x;
        acc.y += w.y * xv.y;
        acc.z += w.z * xv.z;
        acc.w += w.w * xv.w;
    }
    float s = (acc.x + acc.y) + (acc.z + acc.w) + b1[hid];
    ha[(nb + node) * HID + hid] = fmaxf(s, 0.f);
}

// ---------------- layer 1: one wave per node, lane = channel, CSR edges ----------------
// hb[n] = EPS*ha[n] + (1/cnt) * sum_e g_e * nde_e * (ha[row_e] + ha[n])
// (layer 1: raw == ha, so the residual term reuses hcv)
__global__ void agg1_kernel(const float* __restrict__ ha, const int* __restrict__ srow,
                            const float* __restrict__ snde, const int* __restrict__ off,
                            const float* __restrict__ gw, const float* __restrict__ gb,
                            const float* __restrict__ invcnt, float* __restrict__ hb) {
    int t = threadIdx.x;
    int lane = t & 63;
    int node = blockIdx.x * 4 + (t >> 6);
    float wa = gw[lane], wb = gw[HID + lane];
    float hcv = ha[node * HID + lane];
    float hcd = hcv * wb;
#pragma unroll
    for (int s = 1; s < 64; s <<= 1) hcd += __shfl_xor(hcd, s);
    hcd += gb[0];
    float acc = 0.f;
    int e0 = off[node], e1 = off[node + 1];
    int r; float nde = 0.f, hr = 0.f;
    if (e0 < e1) { r = srow[e0]; nde = snde[e0]; hr = ha[r * HID + lane]; }
    for (int e = e0; e < e1; e++) {
        float hr_c = hr, nde_c = nde;
        int e2 = e + 1;
        if (e2 < e1) { r = srow[e2]; nde = snde[e2]; hr = ha[r * HID + lane]; }
        float p = hr_c * wa;
#pragma unroll
        for (int s = 1; s < 64; s <<= 1) p += __shfl_xor(p, s);
        float g = tanhf(p + hcd);
        acc += (g * nde_c) * (hr_c + hcv);
    }
    hb[node * HID + lane] = EPS_RES * hcv + acc * invcnt[node];
}

// ---------------- layer 2 + classifier + log_softmax, fused ----------------
__global__ void agg2_kernel(const float* __restrict__ hb, const float* __restrict__ ha,
                            const int* __restrict__ srow, const float* __restrict__ snde,
                            const int* __restrict__ off, const float* __restrict__ gw,
                            const float* __restrict__ gb, const float* __restrict__ invcnt,
                            const float* __restrict__ W2, const float* __restrict__ b2,
                            float* __restrict__ out) {
    __shared__ float w2s[NCLS * 65];
    __shared__ float b2s[NCLS];
    __shared__ float hs[4 * HID];
    int t = threadIdx.x;
    for (int i = t; i < NCLS * HID; i += 256) w2s[(i >> 6) * 65 + (i & 63)] = W2[i];
    if (t < NCLS) b2s[t] = b2[t];
    int lane = t & 63;
    int wv = t >> 6;
    int node = blockIdx.x * 4 + wv;
    float wa = gw[lane], wb = gw[HID + lane];
    float hcv = hb[node * HID + lane];
    float hcd = hcv * wb;
#pragma unroll
    for (int s = 1; s < 64; s <<= 1) hcd += __shfl_xor(hcd, s);
    hcd += gb[0];
    float acc = 0.f;
    int e0 = off[node], e1 = off[node + 1];
    int r; float nde = 0.f, hr = 0.f;
    if (e0 < e1) { r = srow[e0]; nde = snde[e0]; hr = hb[r * HID + lane]; }
    for (int e = e0; e < e1; e++) {
        float hr_c = hr, nde_c = nde;
        int e2 = e + 1;
        if (e2 < e1) { r = srow[e2]; nde = snde[e2]; hr = hb[r * HID + lane]; }
        float p = hr_c * wa;
#pragma unroll
        for (int s = 1; s < 64; s <<= 1) p += __shfl_xor(p, s);
        float g = tanhf(p + hcd);
        acc += (g * nde_c) * (hr_c + hcv);
    }
    float hval = EPS_RES * ha[node * HID + lane] + acc * invcnt[node];
    hs[wv * HID + lane] = hval;
    __syncthreads();
    // classifier: lanes 0..39 compute one class each for this wave's node
    float logit = 0.f;
    if (lane < NCLS) {
        const float* wr = w2s + lane * 65;
        const float* hrow = hs + wv * HID;
#pragma unroll
        for (int k = 0; k < HID; k++) logit += hrow[k] * wr[k];
        logit += b2s[lane];
    }
    float v = (lane < NCLS) ? logit : -INFINITY;
#pragma unroll
    for (int s = 1; s < 64; s <<= 1) v = fmaxf(v, __shfl_xor(v, s));
    float ex = (lane < NCLS) ? expf(logit - v) : 0.f;
#pragma unroll
    for (int s = 1; s < 64; s <<= 1) ex += __shfl_xor(ex, s);
    float ls = v + logf(ex);
    if (lane < NCLS) out[node * NCLS + lane] = logit - ls;
}

extern "C" void kernel_launch(void* const* d_in, const int* in_sizes, int n_in,
                              void* d_out, int out_size, void* d_ws, size_t ws_size,
                              hipStream_t stream) {
    const float* x  = (const float*)d_in[0];
    const int*   ei = (const int*)d_in[1];
    const float* W1 = (const float*)d_in[2];
    const float* b1 = (const float*)d_in[3];
    const float* W2 = (const float*)d_in[4];
    const float* b2 = (const float*)d_in[5];
    const float* gw = (const float*)d_in[6];
    const float* gb = (const float*)d_in[7];
    float* out = (float*)d_out;

    // ws layout (all 4-byte elems; ha 16B-aligned by construction):
    // [degi N][cnti N][fill N][srow E][nd N][invcnt N][snde E][ha N*H][hb N*H][off N+1]
    int*   degi   = (int*)d_ws;
    int*   cnti   = degi + N_NODES;
    int*   fill   = cnti + N_NODES;
    int*   srow   = fill + N_NODES;
    float* nd     = (float*)(srow + N_EDGES);
    float* invcnt = nd + N_NODES;
    float* snde   = invcnt + N_NODES;
    float* ha     = snde + N_EDGES;
    float* hb     = ha + (size_t)N_NODES * HID;
    int*   off    = (int*)(hb + (size_t)N_NODES * HID);

    const int* row = ei;
    const int* col = ei + N_EDGES;

    // zero degi + cnti + fill (contiguous)
    hipMemsetAsync(degi, 0, (size_t)3 * N_NODES * sizeof(int), stream);

    degree_kernel<<<N_EDGES / 256, 256, 0, stream>>>(row, col, degi, cnti);
    nd_kernel<<<(N_NODES + 255) / 256, 256, 0, stream>>>(degi, cnti, nd, invcnt);
    scan_kernel<<<1, 1024, 0, stream>>>(cnti, off);
    scatter_kernel<<<N_EDGES / 256, 256, 0, stream>>>(row, col, nd, off, fill, srow, snde);
    proj_kernel<<<N_NODES / 4, 256, 0, stream>>>(x, W1, b1, ha);

    agg1_kernel<<<N_NODES / 4, 256, 0, stream>>>(ha, srow, snde, off, gw, gb, invcnt, hb);
    agg2_kernel<<<N_NODES / 4, 256, 0, stream>>>(hb, ha, srow, snde, off, gw + 2 * HID, gb + 1,
                                                 invcnt, W2, b2, out);
}

// Round 3
// 568.066 us; speedup vs baseline: 10.5384x; 1.5781x over previous
//
#include <hip/hip_runtime.h>
#include <math.h>

#define N_NODES 50000
#define N_EDGES 800000
#define NFEAT 256
#define HID 64
#define NCLS 40
#define EPS_RES 0.3f
#define ROWSZ 68  // LDS row pitch in floats (64 + 4 pad, keeps 16B alignment, breaks pow2 banks)

// ---------------- degree / normalization ----------------
__global__ void degree_kernel(const int* __restrict__ row, const int* __restrict__ col,
                              int* __restrict__ degi, int* __restrict__ cnti) {
    int e = blockIdx.x * 256 + threadIdx.x;
    atomicAdd(&degi[row[e]], 1);
    atomicAdd(&cnti[col[e]], 1);
}

__global__ void nd_kernel(const int* __restrict__ degi, const int* __restrict__ cnti,
                          float* __restrict__ nd, float* __restrict__ invcnt) {
    int n = blockIdx.x * 256 + threadIdx.x;
    if (n < N_NODES) {
        int d = degi[n]; if (d < 1) d = 1;
        nd[n] = rsqrtf((float)d);
        int c = cnti[n]; if (c < 1) c = 1;
        invcnt[n] = 1.0f / (float)c;
    }
}

// ---------------- exclusive prefix sum of cnti -> off (single block) ----------------
__global__ void scan_kernel(const int* __restrict__ cnti, int* __restrict__ off) {
    __shared__ int part[1024];
    int t = threadIdx.x;
    const int CH = (N_NODES + 1023) / 1024;
    int base = t * CH;
    int s = 0;
    for (int i = 0; i < CH; i++) { int idx = base + i; if (idx < N_NODES) s += cnti[idx]; }
    part[t] = s;
    __syncthreads();
    for (int d = 1; d < 1024; d <<= 1) {
        int v = (t >= d) ? part[t - d] : 0;
        __syncthreads();
        part[t] += v;
        __syncthreads();
    }
    int excl = part[t] - s;
    for (int i = 0; i < CH; i++) {
        int idx = base + i;
        if (idx < N_NODES) { off[idx] = excl; excl += cnti[idx]; }
    }
    if (t == 0) off[N_NODES] = N_EDGES;
}

// ---------------- counting-sort scatter: edges grouped by target ----------------
__global__ void scatter_kernel(const int* __restrict__ row, const int* __restrict__ col,
                               const int* __restrict__ off, int* __restrict__ fill,
                               int* __restrict__ srow, int* __restrict__ stgt) {
    int e = blockIdx.x * 256 + threadIdx.x;
    int r = row[e], c = col[e];
    int p = off[c] + atomicAdd(&fill[c], 1);
    srow[p] = r;
    stgt[p] = c;
}

// ---------------- input projection: ha = relu(x @ W1^T + b1), LDS-tiled GEMM ----------------
// 64 nodes x 64 hid per block, 256 threads, 16 outputs/thread (4 nodes x 4 hid).
__global__ __launch_bounds__(256) void proj_kernel(const float* __restrict__ x,
                                                   const float* __restrict__ W1,
                                                   const float* __restrict__ b1,
                                                   float* __restrict__ ha) {
    __shared__ float xs[64 * ROWSZ];
    __shared__ float ws[64 * ROWSZ];
    int t = threadIdx.x;
    int nb = blockIdx.x * 64;
    int lane = t & 63, w = t >> 6;
    int l15 = lane & 15, g = lane >> 4;
    int hbase = 16 * w + 4 * g;  // 4 contiguous hids per thread
    float acc[4][4];
#pragma unroll
    for (int j = 0; j < 4; j++)
#pragma unroll
        for (int i = 0; i < 4; i++) acc[j][i] = 0.f;

    for (int kc = 0; kc < NFEAT; kc += 64) {
        __syncthreads();
#pragma unroll
        for (int i = 0; i < 4; i++) {
            int idx = t + 256 * i;       // 0..1023
            int r_ = idx >> 4;           // row 0..63
            int kq = idx & 15;           // 0..15 (x4 floats)
            int gn = nb + r_;
            float4 v = make_float4(0.f, 0.f, 0.f, 0.f);
            if (gn < N_NODES) v = *(const float4*)(x + (size_t)gn * NFEAT + kc + kq * 4);
            *(float4*)(xs + r_ * ROWSZ + kq * 4) = v;
            float4 wv = *(const float4*)(W1 + (size_t)r_ * NFEAT + kc + kq * 4);
            *(float4*)(ws + r_ * ROWSZ + kq * 4) = wv;
        }
        __syncthreads();
#pragma unroll 4
        for (int k = 0; k < 64; k += 4) {
            float4 a[4], b[4];
#pragma unroll
            for (int j = 0; j < 4; j++) a[j] = *(const float4*)(xs + (l15 + 16 * j) * ROWSZ + k);
#pragma unroll
            for (int i = 0; i < 4; i++) b[i] = *(const float4*)(ws + (hbase + i) * ROWSZ + k);
#pragma unroll
            for (int j = 0; j < 4; j++)
#pragma unroll
                for (int i = 0; i < 4; i++)
                    acc[j][i] += a[j].x * b[i].x + a[j].y * b[i].y + a[j].z * b[i].z + a[j].w * b[i].w;
        }
    }
    float4 bias = *(const float4*)(b1 + hbase);
#pragma unroll
    for (int j = 0; j < 4; j++) {
        int gn = nb + l15 + 16 * j;
        if (gn < N_NODES) {
            float4 o;
            o.x = fmaxf(acc[j][0] + bias.x, 0.f);
            o.y = fmaxf(acc[j][1] + bias.y, 0.f);
            o.z = fmaxf(acc[j][2] + bias.z, 0.f);
            o.w = fmaxf(acc[j][3] + bias.w, 0.f);
            *(float4*)(ha + (size_t)gn * HID + hbase) = o;
        }
    }
}

// ---------------- per-node gate projections: y = h.wa, z = h.wb ----------------
__global__ void yz_kernel(const float* __restrict__ h, const float* __restrict__ gw,
                          float* __restrict__ y, float* __restrict__ z) {
    int t = threadIdx.x;
    int lane = t & 63;
    int node = blockIdx.x * 4 + (t >> 6);
    float wa = gw[lane], wb = gw[HID + lane];
    float v = h[node * HID + lane];
    float p = v * wa, q = v * wb;
#pragma unroll
    for (int s = 1; s < 64; s <<= 1) { p += __shfl_xor(p, s); q += __shfl_xor(q, s); }
    if (lane == 0) { y[node] = p; z[node] = q; }
}

// ---------------- edge-parallel gate: gnde = tanh(y[r]+z[c]+b) * nd[r]*nd[c] ----------------
__global__ void gate_kernel(const int* __restrict__ srow, const int* __restrict__ stgt,
                            const float* __restrict__ nd, const float* __restrict__ y,
                            const float* __restrict__ z, const float* __restrict__ gb,
                            float* __restrict__ gnde) {
    int e = blockIdx.x * 256 + threadIdx.x;
    int r = srow[e], c = stgt[e];
    float g = tanhf(y[r] + z[c] + gb[0]);
    gnde[e] = g * nd[r] * nd[c];
}

// ---------------- CSR aggregation core: sum gnde*h[r] + (sum gnde)*h[c] ----------------
__device__ __forceinline__ float agg_core(const float* __restrict__ h, const int* __restrict__ srow,
                                          const float* __restrict__ gnde, int e0, int e1,
                                          int lane, float hcv, float raw_v, float invc) {
    float acc = 0.f, gs = 0.f;
    int cnt = e1 - e0;
    int r1 = 0, r2 = 0;
    float g1 = 0.f, g2 = 0.f, hr1 = 0.f;
    if (cnt > 0) { r1 = srow[e0]; g1 = gnde[e0]; hr1 = h[(size_t)r1 * HID + lane]; }
    if (cnt > 1) { r2 = srow[e0 + 1]; g2 = gnde[e0 + 1]; }
    for (int i = 0; i < cnt; i++) {
        float hr_c = hr1, gn_c = g1;
        int rn = r2; float gn2 = g2;
        int e2 = e0 + i + 2;
        if (e2 < e1) { r2 = srow[e2]; g2 = gnde[e2]; } else { r2 = 0; g2 = 0.f; }
        if (i + 1 < cnt) { hr1 = h[(size_t)rn * HID + lane]; g1 = gn2; } else { hr1 = 0.f; g1 = 0.f; }
        acc += gn_c * hr_c;
        gs += gn_c;
    }
    return EPS_RES * raw_v + (acc + gs * hcv) * invc;
}

// ---------------- layer 1 agg + fused y2/z2 ----------------
__global__ void agg1_kernel(const float* __restrict__ ha, const int* __restrict__ srow,
                            const float* __restrict__ gnde, const int* __restrict__ off,
                            const float* __restrict__ invcnt, const float* __restrict__ gw2,
                            float* __restrict__ hb, float* __restrict__ y2, float* __restrict__ z2) {
    int t = threadIdx.x;
    int lane = t & 63;
    int node = blockIdx.x * 4 + (t >> 6);
    float hcv = ha[node * HID + lane];
    float hval = agg_core(ha, srow, gnde, off[node], off[node + 1], lane, hcv, hcv, invcnt[node]);
    hb[node * HID + lane] = hval;
    float p = hval * gw2[lane], q = hval * gw2[HID + lane];
#pragma unroll
    for (int s = 1; s < 64; s <<= 1) { p += __shfl_xor(p, s); q += __shfl_xor(q, s); }
    if (lane == 0) { y2[node] = p; z2[node] = q; }
}

// ---------------- layer 2 agg + classifier + log_softmax ----------------
__global__ void agg2_kernel(const float* __restrict__ hb, const float* __restrict__ ha,
                            const int* __restrict__ srow, const float* __restrict__ gnde,
                            const int* __restrict__ off, const float* __restrict__ invcnt,
                            const float* __restrict__ W2, const float* __restrict__ b2,
                            float* __restrict__ out) {
    __shared__ float w2s[NCLS * 65];
    __shared__ float b2s[NCLS];
    __shared__ float hs[4 * HID];
    int t = threadIdx.x;
    for (int i = t; i < NCLS * HID; i += 256) w2s[(i >> 6) * 65 + (i & 63)] = W2[i];
    if (t < NCLS) b2s[t] = b2[t];
    int lane = t & 63;
    int wv = t >> 6;
    int node = blockIdx.x * 4 + wv;
    float hcv = hb[node * HID + lane];
    float raw_v = ha[node * HID + lane];
    float hval = agg_core(hb, srow, gnde, off[node], off[node + 1], lane, hcv, raw_v, invcnt[node]);
    hs[wv * HID + lane] = hval;
    __syncthreads();
    float logit = 0.f;
    if (lane < NCLS) {
        const float* wr = w2s + lane * 65;
        const float* hrow = hs + wv * HID;
#pragma unroll
        for (int k = 0; k < HID; k++) logit += hrow[k] * wr[k];
        logit += b2s[lane];
    }
    float v = (lane < NCLS) ? logit : -INFINITY;
#pragma unroll
    for (int s = 1; s < 64; s <<= 1) v = fmaxf(v, __shfl_xor(v, s));
    float ex = (lane < NCLS) ? expf(logit - v) : 0.f;
#pragma unroll
    for (int s = 1; s < 64; s <<= 1) ex += __shfl_xor(ex, s);
    float ls = v + logf(ex);
    if (lane < NCLS) out[node * NCLS + lane] = logit - ls;
}

extern "C" void kernel_launch(void* const* d_in, const int* in_sizes, int n_in,
                              void* d_out, int out_size, void* d_ws, size_t ws_size,
                              hipStream_t stream) {
    const float* x  = (const float*)d_in[0];
    const int*   ei = (const int*)d_in[1];
    const float* W1 = (const float*)d_in[2];
    const float* b1 = (const float*)d_in[3];
    const float* W2 = (const float*)d_in[4];
    const float* b2 = (const float*)d_in[5];
    const float* gw = (const float*)d_in[6];
    const float* gb = (const float*)d_in[7];
    float* out = (float*)d_out;

    // ws layout: [degi N][cnti N][fill N][srow E][stgt E][gnde E][nd N][invcnt N][y N][z N]
    //            [ha N*H][hb N*H][off N+1]   total ~36.8 MB
    int*   degi   = (int*)d_ws;
    int*   cnti   = degi + N_NODES;
    int*   fill   = cnti + N_NODES;
    int*   srow   = fill + N_NODES;
    int*   stgt   = srow + N_EDGES;
    float* gnde   = (float*)(stgt + N_EDGES);
    float* nd     = gnde + N_EDGES;
    float* invcnt = nd + N_NODES;
    float* y      = invcnt + N_NODES;
    float* z      = y + N_NODES;
    float* ha     = z + N_NODES;
    float* hb     = ha + (size_t)N_NODES * HID;
    int*   off    = (int*)(hb + (size_t)N_NODES * HID);

    const int* row = ei;
    const int* col = ei + N_EDGES;

    hipMemsetAsync(degi, 0, (size_t)3 * N_NODES * sizeof(int), stream);

    degree_kernel<<<N_EDGES / 256, 256, 0, stream>>>(row, col, degi, cnti);
    nd_kernel<<<(N_NODES + 255) / 256, 256, 0, stream>>>(degi, cnti, nd, invcnt);
    scan_kernel<<<1, 1024, 0, stream>>>(cnti, off);
    scatter_kernel<<<N_EDGES / 256, 256, 0, stream>>>(row, col, off, fill, srow, stgt);
    proj_kernel<<<(N_NODES + 63) / 64, 256, 0, stream>>>(x, W1, b1, ha);
    yz_kernel<<<N_NODES / 4, 256, 0, stream>>>(ha, gw, y, z);

    gate_kernel<<<N_EDGES / 256, 256, 0, stream>>>(srow, stgt, nd, y, z, gb, gnde);
    agg1_kernel<<<N_NODES / 4, 256, 0, stream>>>(ha, srow, gnde, off, invcnt, gw + 2 * HID, hb, y, z);

    gate_kernel<<<N_EDGES / 256, 256, 0, stream>>>(srow, stgt, nd, y, z, gb + 1, gnde);
    agg2_kernel<<<N_NODES / 4, 256, 0, stream>>>(hb, ha, srow, gnde, off, invcnt, W2, b2, out);
}

// Round 4
// 433.812 us; speedup vs baseline: 13.7997x; 1.3095x over previous
//
#include <hip/hip_runtime.h>
#include <math.h>

#define N_NODES 50000
#define N_EDGES 800000
#define NFEAT 256
#define HID 64
#define NCLS 40
#define EPS_RES 0.3f
#define ROWSZ 68  // LDS row pitch for proj (64 + 4 pad)

// ---------------- degree + per-edge rank (rank = position within target's CSR bucket) ----
__global__ void degree_kernel(const int* __restrict__ row, const int* __restrict__ col,
                              int* __restrict__ degi, int* __restrict__ cnti,
                              int* __restrict__ rankc) {
    int e = blockIdx.x * 256 + threadIdx.x;
    atomicAdd(&degi[row[e]], 1);
    rankc[e] = atomicAdd(&cnti[col[e]], 1);
}

__global__ void nd_kernel(const int* __restrict__ degi, const int* __restrict__ cnti,
                          float* __restrict__ nd, float* __restrict__ invcnt) {
    int n = blockIdx.x * 256 + threadIdx.x;
    if (n < N_NODES) {
        int d = degi[n]; if (d < 1) d = 1;
        nd[n] = rsqrtf((float)d);
        int c = cnti[n]; if (c < 1) c = 1;
        invcnt[n] = 1.0f / (float)c;
    }
}

// ---------------- exclusive prefix sum of cnti -> off (single block) ----------------
__global__ void scan_kernel(const int* __restrict__ cnti, int* __restrict__ off) {
    __shared__ int part[1024];
    int t = threadIdx.x;
    const int CH = (N_NODES + 1023) / 1024;
    int base = t * CH;
    int s = 0;
    for (int i = 0; i < CH; i++) { int idx = base + i; if (idx < N_NODES) s += cnti[idx]; }
    part[t] = s;
    __syncthreads();
    for (int d = 1; d < 1024; d <<= 1) {
        int v = (t >= d) ? part[t - d] : 0;
        __syncthreads();
        part[t] += v;
        __syncthreads();
    }
    int excl = part[t] - s;
    for (int i = 0; i < CH; i++) {
        int idx = base + i;
        if (idx < N_NODES) { off[idx] = excl; excl += cnti[idx]; }
    }
    if (t == 0) off[N_NODES] = N_EDGES;
}

// ---------------- CSR scatter (no atomics: rank precomputed) + snde ----------------
__global__ void scatter_kernel(const int* __restrict__ row, const int* __restrict__ col,
                               const int* __restrict__ rankc, const int* __restrict__ off,
                               const float* __restrict__ nd, int* __restrict__ srow,
                               float* __restrict__ snde) {
    int e = blockIdx.x * 256 + threadIdx.x;
    int r = row[e], c = col[e];
    int p = off[c] + rankc[e];
    srow[p] = r;
    snde[p] = nd[r] * nd[c];
}

// ---------------- input projection: ha = relu(x @ W1^T + b1), LDS-tiled GEMM ----------------
__global__ __launch_bounds__(256) void proj_kernel(const float* __restrict__ x,
                                                   const float* __restrict__ W1,
                                                   const float* __restrict__ b1,
                                                   float* __restrict__ ha) {
    __shared__ float xs[64 * ROWSZ];
    __shared__ float ws[64 * ROWSZ];
    int t = threadIdx.x;
    int nb = blockIdx.x * 64;
    int lane = t & 63, w = t >> 6;
    int l15 = lane & 15, g = lane >> 4;
    int hbase = 16 * w + 4 * g;
    float acc[4][4];
#pragma unroll
    for (int j = 0; j < 4; j++)
#pragma unroll
        for (int i = 0; i < 4; i++) acc[j][i] = 0.f;

    for (int kc = 0; kc < NFEAT; kc += 64) {
        __syncthreads();
#pragma unroll
        for (int i = 0; i < 4; i++) {
            int idx = t + 256 * i;
            int r_ = idx >> 4;
            int kq = idx & 15;
            int gn = nb + r_;
            float4 v = make_float4(0.f, 0.f, 0.f, 0.f);
            if (gn < N_NODES) v = *(const float4*)(x + (size_t)gn * NFEAT + kc + kq * 4);
            *(float4*)(xs + r_ * ROWSZ + kq * 4) = v;
            float4 wv = *(const float4*)(W1 + (size_t)r_ * NFEAT + kc + kq * 4);
            *(float4*)(ws + r_ * ROWSZ + kq * 4) = wv;
        }
        __syncthreads();
#pragma unroll 4
        for (int k = 0; k < 64; k += 4) {
            float4 a[4], b[4];
#pragma unroll
            for (int j = 0; j < 4; j++) a[j] = *(const float4*)(xs + (l15 + 16 * j) * ROWSZ + k);
#pragma unroll
            for (int i = 0; i < 4; i++) b[i] = *(const float4*)(ws + (hbase + i) * ROWSZ + k);
#pragma unroll
            for (int j = 0; j < 4; j++)
#pragma unroll
                for (int i = 0; i < 4; i++)
                    acc[j][i] += a[j].x * b[i].x + a[j].y * b[i].y + a[j].z * b[i].z + a[j].w * b[i].w;
        }
    }
    float4 bias = *(const float4*)(b1 + hbase);
#pragma unroll
    for (int j = 0; j < 4; j++) {
        int gn = nb + l15 + 16 * j;
        if (gn < N_NODES) {
            float4 o;
            o.x = fmaxf(acc[j][0] + bias.x, 0.f);
            o.y = fmaxf(acc[j][1] + bias.y, 0.f);
            o.z = fmaxf(acc[j][2] + bias.z, 0.f);
            o.w = fmaxf(acc[j][3] + bias.w, 0.f);
            *(float4*)(ha + (size_t)gn * HID + hbase) = o;
        }
    }
}

// ---------------- per-node gate projections: y = h.wa, z = h.wb ----------------
__global__ void yz_kernel(const float* __restrict__ h, const float* __restrict__ gw,
                          float* __restrict__ y, float* __restrict__ z) {
    int t = threadIdx.x;
    int lane = t & 63;
    int node = blockIdx.x * 4 + (t >> 6);
    float wa = gw[lane], wb = gw[HID + lane];
    float v = h[node * HID + lane];
    float p = v * wa, q = v * wb;
#pragma unroll
    for (int s = 1; s < 64; s <<= 1) { p += __shfl_xor(p, s); q += __shfl_xor(q, s); }
    if (lane == 0) { y[node] = p; z[node] = q; }
}

// ---------------- CSR aggregation core: 4 edges/iter, fused gate ----------------
// lane group q=lane>>4 owns edge slot q; each lane holds 4 channels (float4).
// out = EPS*raw + ( sum_e g_e*h[r_e] + (sum_e g_e)*hc ) * invc,  g_e = tanh(y[r]+zc_b)*nde
__device__ __forceinline__ float4 agg_core4(const float* __restrict__ h,
                                            const int* __restrict__ srow,
                                            const float* __restrict__ snde,
                                            const float* __restrict__ y,
                                            float zc_b, int e0, int e1, int q, int c4,
                                            float4 hcv4, float4 raw4, float invc) {
    float4 acc = make_float4(0.f, 0.f, 0.f, 0.f);
    float gs = 0.f;
    if (e0 < e1) {
        int e = e0 + q;
        int ec = (e < e1) ? e : e0;
        int r_n = srow[ec];
        float nde_n = (e < e1) ? snde[ec] : 0.f;
        float y_n = y[r_n];
        float4 hr_n = *(const float4*)(h + (size_t)r_n * HID + c4);
        for (int base = e0; base < e1; base += 4) {
            int e2 = base + 4 + q;
            int ec2 = (e2 < e1) ? e2 : e0;
            int r2 = srow[ec2];
            float nde2 = (e2 < e1) ? snde[ec2] : 0.f;
            float y2v = y[r2];
            float4 hr2 = *(const float4*)(h + (size_t)r2 * HID + c4);
            float g = tanhf(y_n + zc_b) * nde_n;
            acc.x += g * hr_n.x;
            acc.y += g * hr_n.y;
            acc.z += g * hr_n.z;
            acc.w += g * hr_n.w;
            gs += g;
            r_n = r2; nde_n = nde2; y_n = y2v; hr_n = hr2;
        }
    }
#pragma unroll
    for (int s = 16; s < 64; s <<= 1) {
        acc.x += __shfl_xor(acc.x, s);
        acc.y += __shfl_xor(acc.y, s);
        acc.z += __shfl_xor(acc.z, s);
        acc.w += __shfl_xor(acc.w, s);
        gs += __shfl_xor(gs, s);
    }
    float4 o;
    o.x = EPS_RES * raw4.x + (acc.x + gs * hcv4.x) * invc;
    o.y = EPS_RES * raw4.y + (acc.y + gs * hcv4.y) * invc;
    o.z = EPS_RES * raw4.z + (acc.z + gs * hcv4.z) * invc;
    o.w = EPS_RES * raw4.w + (acc.w + gs * hcv4.w) * invc;
    return o;
}

// ---------------- layer 1 agg + fused y2/z2 ----------------
__global__ void agg1_kernel(const float* __restrict__ ha, const int* __restrict__ srow,
                            const float* __restrict__ snde, const int* __restrict__ off,
                            const float* __restrict__ invcnt, const float* __restrict__ y,
                            const float* __restrict__ z, const float* __restrict__ gb,
                            const float* __restrict__ gw2, float* __restrict__ hb,
                            float* __restrict__ y2, float* __restrict__ z2) {
    int t = threadIdx.x;
    int lane = t & 63;
    int node = blockIdx.x * 4 + (t >> 6);
    int q = lane >> 4, c4 = (lane & 15) * 4;
    float4 hcv4 = *(const float4*)(ha + (size_t)node * HID + c4);
    float zc_b = z[node] + gb[0];
    float4 o = agg_core4(ha, srow, snde, y, zc_b, off[node], off[node + 1], q, c4,
                         hcv4, hcv4, invcnt[node]);
    if (q == 0) *(float4*)(hb + (size_t)node * HID + c4) = o;
    // fused layer-2 gate projections
    float4 wa4 = *(const float4*)(gw2 + c4);
    float4 wb4 = *(const float4*)(gw2 + HID + c4);
    float p = o.x * wa4.x + o.y * wa4.y + o.z * wa4.z + o.w * wa4.w;
    float qq = o.x * wb4.x + o.y * wb4.y + o.z * wb4.z + o.w * wb4.w;
#pragma unroll
    for (int s = 1; s < 16; s <<= 1) { p += __shfl_xor(p, s); qq += __shfl_xor(qq, s); }
    if (lane == 0) { y2[node] = p; z2[node] = qq; }
}

// ---------------- layer 2 agg + classifier + log_softmax ----------------
__global__ void agg2_kernel(const float* __restrict__ hb, const float* __restrict__ ha,
                            const int* __restrict__ srow, const float* __restrict__ snde,
                            const int* __restrict__ off, const float* __restrict__ invcnt,
                            const float* __restrict__ y2, const float* __restrict__ z2,
                            const float* __restrict__ gb, const float* __restrict__ W2,
                            const float* __restrict__ b2, float* __restrict__ out) {
    __shared__ float w2s[NCLS * 65];
    __shared__ float b2s[NCLS];
    __shared__ float hs[4 * HID];
    int t = threadIdx.x;
    for (int i = t; i < NCLS * HID; i += 256) w2s[(i >> 6) * 65 + (i & 63)] = W2[i];
    if (t < NCLS) b2s[t] = b2[t];
    int lane = t & 63;
    int wv = t >> 6;
    int node = blockIdx.x * 4 + wv;
    int q = lane >> 4, c4 = (lane & 15) * 4;
    float4 hcv4 = *(const float4*)(hb + (size_t)node * HID + c4);
    float4 raw4 = *(const float4*)(ha + (size_t)node * HID + c4);
    float zc_b = z2[node] + gb[0];
    float4 o = agg_core4(hb, srow, snde, y2, zc_b, off[node], off[node + 1], q, c4,
                         hcv4, raw4, invcnt[node]);
    if (q == 0) *(float4*)(hs + wv * HID + c4) = o;
    __syncthreads();
    float logit = 0.f;
    if (lane < NCLS) {
        const float* wr = w2s + lane * 65;
        const float* hrow = hs + wv * HID;
#pragma unroll
        for (int k = 0; k < HID; k++) logit += hrow[k] * wr[k];
        logit += b2s[lane];
    }
    float v = (lane < NCLS) ? logit : -INFINITY;
#pragma unroll
    for (int s = 1; s < 64; s <<= 1) v = fmaxf(v, __shfl_xor(v, s));
    float ex = (lane < NCLS) ? expf(logit - v) : 0.f;
#pragma unroll
    for (int s = 1; s < 64; s <<= 1) ex += __shfl_xor(ex, s);
    float ls = v + logf(ex);
    if (lane < NCLS) out[node * NCLS + lane] = logit - ls;
}

extern "C" void kernel_launch(void* const* d_in, const int* in_sizes, int n_in,
                              void* d_out, int out_size, void* d_ws, size_t ws_size,
                              hipStream_t stream) {
    const float* x  = (const float*)d_in[0];
    const int*   ei = (const int*)d_in[1];
    const float* W1 = (const float*)d_in[2];
    const float* b1 = (const float*)d_in[3];
    const float* W2 = (const float*)d_in[4];
    const float* b2 = (const float*)d_in[5];
    const float* gw = (const float*)d_in[6];
    const float* gb = (const float*)d_in[7];
    float* out = (float*)d_out;

    // ws layout (floats): [degi N][cnti N][srow E][snde E][nd N][invcnt N][y N][z N][y2 N][z2 N]
    //                     [ha N*H][hb N*H][off N+1];  rankc aliases hb (dead before agg1 writes hb)
    // total = 2N + 2E + 6N + 2NH + N+1 = 8.45M floats = 33.8 MB
    int*   degi   = (int*)d_ws;
    int*   cnti   = degi + N_NODES;
    int*   srow   = cnti + N_NODES;
    float* snde   = (float*)(srow + N_EDGES);
    float* nd     = snde + N_EDGES;
    float* invcnt = nd + N_NODES;
    float* y      = invcnt + N_NODES;
    float* z      = y + N_NODES;
    float* y2     = z + N_NODES;
    float* z2     = y2 + N_NODES;
    float* ha     = z2 + N_NODES;
    float* hb     = ha + (size_t)N_NODES * HID;
    int*   off    = (int*)(hb + (size_t)N_NODES * HID);
    int*   rankc  = (int*)hb;  // E ints <= N*H floats, dead before agg1 writes hb

    const int* row = ei;
    const int* col = ei + N_EDGES;

    hipMemsetAsync(degi, 0, (size_t)2 * N_NODES * sizeof(int), stream);

    degree_kernel<<<N_EDGES / 256, 256, 0, stream>>>(row, col, degi, cnti, rankc);
    nd_kernel<<<(N_NODES + 255) / 256, 256, 0, stream>>>(degi, cnti, nd, invcnt);
    scan_kernel<<<1, 1024, 0, stream>>>(cnti, off);
    scatter_kernel<<<N_EDGES / 256, 256, 0, stream>>>(row, col, rankc, off, nd, srow, snde);
    proj_kernel<<<(N_NODES + 63) / 64, 256, 0, stream>>>(x, W1, b1, ha);
    yz_kernel<<<N_NODES / 4, 256, 0, stream>>>(ha, gw, y, z);

    agg1_kernel<<<N_NODES / 4, 256, 0, stream>>>(ha, srow, snde, off, invcnt, y, z, gb,
                                                 gw + 2 * HID, hb, y2, z2);
    agg2_kernel<<<N_NODES / 4, 256, 0, stream>>>(hb, ha, srow, snde, off, invcnt, y2, z2,
                                                 gb + 1, W2, b2, out);
}

// Round 5
// 350.602 us; speedup vs baseline: 17.0749x; 1.2373x over previous
//
#include <hip/hip_runtime.h>
#include <math.h>

#define N_NODES 50000
#define N_EDGES 800000
#define NFEAT 256
#define HID 64
#define NCLS 40
#define EPS_RES 0.3f
#define ROWSZ 68  // LDS row pitch for proj (64 + 4 pad)
#define SCAN_BLOCKS ((N_NODES + 255) / 256)  // 196

// ---------------- degree + per-edge rank (rank = position within target's CSR bucket) ----
__global__ void degree_kernel(const int* __restrict__ row, const int* __restrict__ col,
                              int* __restrict__ degi, int* __restrict__ cnti,
                              int* __restrict__ rankc) {
    int e = blockIdx.x * 256 + threadIdx.x;
    atomicAdd(&degi[row[e]], 1);
    rankc[e] = atomicAdd(&cnti[col[e]], 1);
}

__global__ void nd_kernel(const int* __restrict__ degi, const int* __restrict__ cnti,
                          float* __restrict__ nd, float* __restrict__ invcnt) {
    int n = blockIdx.x * 256 + threadIdx.x;
    if (n < N_NODES) {
        int d = degi[n]; if (d < 1) d = 1;
        nd[n] = rsqrtf((float)d);
        int c = cnti[n]; if (c < 1) c = 1;
        invcnt[n] = 1.0f / (float)c;
    }
}

// ---------------- 3-phase grid-wide exclusive scan of cnti -> off ----------------
__device__ __forceinline__ int block_excl_scan_256(int v, int t, int* wsum) {
    int lane = t & 63, w = t >> 6;
    int sv = v;
#pragma unroll
    for (int d = 1; d < 64; d <<= 1) {
        int o = __shfl_up(sv, d);
        if (lane >= d) sv += o;
    }
    if (lane == 63) wsum[w] = sv;
    __syncthreads();
    int add = 0;
    for (int i = 0; i < w; i++) add += wsum[i];
    return sv + add - v;  // exclusive prefix within block
}

__global__ void scan1_kernel(const int* __restrict__ cnti, int* __restrict__ off,
                             int* __restrict__ bsum) {
    __shared__ int wsum[4];
    int t = threadIdx.x;
    int idx = blockIdx.x * 256 + t;
    int v = (idx < N_NODES) ? cnti[idx] : 0;
    int excl = block_excl_scan_256(v, t, wsum);
    if (idx < N_NODES) off[idx] = excl;
    if (t == 255) bsum[blockIdx.x] = excl + v;  // block total
}

__global__ void scan2_kernel(int* __restrict__ bsum) {
    __shared__ int wsum[4];
    int t = threadIdx.x;
    int v = (t < SCAN_BLOCKS) ? bsum[t] : 0;
    int excl = block_excl_scan_256(v, t, wsum);
    if (t < SCAN_BLOCKS) bsum[t] = excl;
}

__global__ void scan3_kernel(int* __restrict__ off, const int* __restrict__ bsum) {
    int t = threadIdx.x;
    int idx = blockIdx.x * 256 + t;
    if (idx < N_NODES) off[idx] += bsum[blockIdx.x];
    if (idx == 0) off[N_NODES] = N_EDGES;
}

// ---------------- CSR scatter (no atomics: rank precomputed) + snde ----------------
__global__ void scatter_kernel(const int* __restrict__ row, const int* __restrict__ col,
                               const int* __restrict__ rankc, const int* __restrict__ off,
                               const float* __restrict__ nd, int* __restrict__ srow,
                               float* __restrict__ snde) {
    int e = blockIdx.x * 256 + threadIdx.x;
    int r = row[e], c = col[e];
    int p = off[c] + rankc[e];
    srow[p] = r;
    snde[p] = nd[r] * nd[c];
}

// ---------------- input projection: ha = relu(x @ W1^T + b1), LDS-tiled GEMM ----------------
__global__ __launch_bounds__(256) void proj_kernel(const float* __restrict__ x,
                                                   const float* __restrict__ W1,
                                                   const float* __restrict__ b1,
                                                   float* __restrict__ ha) {
    __shared__ float xs[64 * ROWSZ];
    __shared__ float ws[64 * ROWSZ];
    int t = threadIdx.x;
    int nb = blockIdx.x * 64;
    int lane = t & 63, w = t >> 6;
    int l15 = lane & 15, g = lane >> 4;
    int hbase = 16 * w + 4 * g;
    float acc[4][4];
#pragma unroll
    for (int j = 0; j < 4; j++)
#pragma unroll
        for (int i = 0; i < 4; i++) acc[j][i] = 0.f;

    for (int kc = 0; kc < NFEAT; kc += 64) {
        __syncthreads();
#pragma unroll
        for (int i = 0; i < 4; i++) {
            int idx = t + 256 * i;
            int r_ = idx >> 4;
            int kq = idx & 15;
            int gn = nb + r_;
            float4 v = make_float4(0.f, 0.f, 0.f, 0.f);
            if (gn < N_NODES) v = *(const float4*)(x + (size_t)gn * NFEAT + kc + kq * 4);
            *(float4*)(xs + r_ * ROWSZ + kq * 4) = v;
            float4 wv = *(const float4*)(W1 + (size_t)r_ * NFEAT + kc + kq * 4);
            *(float4*)(ws + r_ * ROWSZ + kq * 4) = wv;
        }
        __syncthreads();
#pragma unroll 4
        for (int k = 0; k < 64; k += 4) {
            float4 a[4], b[4];
#pragma unroll
            for (int j = 0; j < 4; j++) a[j] = *(const float4*)(xs + (l15 + 16 * j) * ROWSZ + k);
#pragma unroll
            for (int i = 0; i < 4; i++) b[i] = *(const float4*)(ws + (hbase + i) * ROWSZ + k);
#pragma unroll
            for (int j = 0; j < 4; j++)
#pragma unroll
                for (int i = 0; i < 4; i++)
                    acc[j][i] += a[j].x * b[i].x + a[j].y * b[i].y + a[j].z * b[i].z + a[j].w * b[i].w;
        }
    }
    float4 bias = *(const float4*)(b1 + hbase);
#pragma unroll
    for (int j = 0; j < 4; j++) {
        int gn = nb + l15 + 16 * j;
        if (gn < N_NODES) {
            float4 o;
            o.x = fmaxf(acc[j][0] + bias.x, 0.f);
            o.y = fmaxf(acc[j][1] + bias.y, 0.f);
            o.z = fmaxf(acc[j][2] + bias.z, 0.f);
            o.w = fmaxf(acc[j][3] + bias.w, 0.f);
            *(float4*)(ha + (size_t)gn * HID + hbase) = o;
        }
    }
}

// ---------------- per-node gate projections: y = h.wa, z = h.wb ----------------
__global__ void yz_kernel(const float* __restrict__ h, const float* __restrict__ gw,
                          float* __restrict__ y, float* __restrict__ z) {
    int t = threadIdx.x;
    int lane = t & 63;
    int node = blockIdx.x * 4 + (t >> 6);
    float wa = gw[lane], wb = gw[HID + lane];
    float v = h[node * HID + lane];
    float p = v * wa, q = v * wb;
#pragma unroll
    for (int s = 1; s < 64; s <<= 1) { p += __shfl_xor(p, s); q += __shfl_xor(q, s); }
    if (lane == 0) { y[node] = p; z[node] = q; }
}

// ---------------- CSR aggregation core: 4 edges/iter, fused gate ----------------
__device__ __forceinline__ float4 agg_core4(const float* __restrict__ h,
                                            const int* __restrict__ srow,
                                            const float* __restrict__ snde,
                                            const float* __restrict__ y,
                                            float zc_b, int e0, int e1, int q, int c4,
                                            float4 hcv4, float4 raw4, float invc) {
    float4 acc = make_float4(0.f, 0.f, 0.f, 0.f);
    float gs = 0.f;
    if (e0 < e1) {
        int e = e0 + q;
        int ec = (e < e1) ? e : e0;
        int r_n = srow[ec];
        float nde_n = (e < e1) ? snde[ec] : 0.f;
        float y_n = y[r_n];
        float4 hr_n = *(const float4*)(h + (size_t)r_n * HID + c4);
        for (int base = e0; base < e1; base += 4) {
            int e2 = base + 4 + q;
            int ec2 = (e2 < e1) ? e2 : e0;
            int r2 = srow[ec2];
            float nde2 = (e2 < e1) ? snde[ec2] : 0.f;
            float y2v = y[r2];
            float4 hr2 = *(const float4*)(h + (size_t)r2 * HID + c4);
            float g = tanhf(y_n + zc_b) * nde_n;
            acc.x += g * hr_n.x;
            acc.y += g * hr_n.y;
            acc.z += g * hr_n.z;
            acc.w += g * hr_n.w;
            gs += g;
            r_n = r2; nde_n = nde2; y_n = y2v; hr_n = hr2;
        }
    }
#pragma unroll
    for (int s = 16; s < 64; s <<= 1) {
        acc.x += __shfl_xor(acc.x, s);
        acc.y += __shfl_xor(acc.y, s);
        acc.z += __shfl_xor(acc.z, s);
        acc.w += __shfl_xor(acc.w, s);
        gs += __shfl_xor(gs, s);
    }
    float4 o;
    o.x = EPS_RES * raw4.x + (acc.x + gs * hcv4.x) * invc;
    o.y = EPS_RES * raw4.y + (acc.y + gs * hcv4.y) * invc;
    o.z = EPS_RES * raw4.z + (acc.z + gs * hcv4.z) * invc;
    o.w = EPS_RES * raw4.w + (acc.w + gs * hcv4.w) * invc;
    return o;
}

// ---------------- layer 1 agg + fused y2/z2 ----------------
__global__ void agg1_kernel(const float* __restrict__ ha, const int* __restrict__ srow,
                            const float* __restrict__ snde, const int* __restrict__ off,
                            const float* __restrict__ invcnt, const float* __restrict__ y,
                            const float* __restrict__ z, const float* __restrict__ gb,
                            const float* __restrict__ gw2, float* __restrict__ hb,
                            float* __restrict__ y2, float* __restrict__ z2) {
    int t = threadIdx.x;
    int lane = t & 63;
    int node = blockIdx.x * 4 + (t >> 6);
    int q = lane >> 4, c4 = (lane & 15) * 4;
    float4 hcv4 = *(const float4*)(ha + (size_t)node * HID + c4);
    float zc_b = z[node] + gb[0];
    float4 o = agg_core4(ha, srow, snde, y, zc_b, off[node], off[node + 1], q, c4,
                         hcv4, hcv4, invcnt[node]);
    if (q == 0) *(float4*)(hb + (size_t)node * HID + c4) = o;
    // fused layer-2 gate projections
    float4 wa4 = *(const float4*)(gw2 + c4);
    float4 wb4 = *(const float4*)(gw2 + HID + c4);
    float p = o.x * wa4.x + o.y * wa4.y + o.z * wa4.z + o.w * wa4.w;
    float qq = o.x * wb4.x + o.y * wb4.y + o.z * wb4.z + o.w * wb4.w;
#pragma unroll
    for (int s = 1; s < 16; s <<= 1) { p += __shfl_xor(p, s); qq += __shfl_xor(qq, s); }
    if (lane == 0) { y2[node] = p; z2[node] = qq; }
}

// ---------------- layer 2 agg + classifier + log_softmax ----------------
__global__ void agg2_kernel(const float* __restrict__ hb, const float* __restrict__ ha,
                            const int* __restrict__ srow, const float* __restrict__ snde,
                            const int* __restrict__ off, const float* __restrict__ invcnt,
                            const float* __restrict__ y2, const float* __restrict__ z2,
                            const float* __restrict__ gb, const float* __restrict__ W2,
                            const float* __restrict__ b2, float* __restrict__ out) {
    __shared__ float w2s[NCLS * 65];
    __shared__ float b2s[NCLS];
    __shared__ float hs[4 * HID];
    int t = threadIdx.x;
    for (int i = t; i < NCLS * HID; i += 256) w2s[(i >> 6) * 65 + (i & 63)] = W2[i];
    if (t < NCLS) b2s[t] = b2[t];
    int lane = t & 63;
    int wv = t >> 6;
    int node = blockIdx.x * 4 + wv;
    int q = lane >> 4, c4 = (lane & 15) * 4;
    float4 hcv4 = *(const float4*)(hb + (size_t)node * HID + c4);
    float4 raw4 = *(const float4*)(ha + (size_t)node * HID + c4);
    float zc_b = z2[node] + gb[0];
    float4 o = agg_core4(hb, srow, snde, y2, zc_b, off[node], off[node + 1], q, c4,
                         hcv4, raw4, invcnt[node]);
    if (q == 0) *(float4*)(hs + wv * HID + c4) = o;
    __syncthreads();
    float logit = 0.f;
    if (lane < NCLS) {
        const float* wr = w2s + lane * 65;
        const float* hrow = hs + wv * HID;
#pragma unroll
        for (int k = 0; k < HID; k++) logit += hrow[k] * wr[k];
        logit += b2s[lane];
    }
    float v = (lane < NCLS) ? logit : -INFINITY;
#pragma unroll
    for (int s = 1; s < 64; s <<= 1) v = fmaxf(v, __shfl_xor(v, s));
    float ex = (lane < NCLS) ? expf(logit - v) : 0.f;
#pragma unroll
    for (int s = 1; s < 64; s <<= 1) ex += __shfl_xor(ex, s);
    float ls = v + logf(ex);
    if (lane < NCLS) out[node * NCLS + lane] = logit - ls;
}

extern "C" void kernel_launch(void* const* d_in, const int* in_sizes, int n_in,
                              void* d_out, int out_size, void* d_ws, size_t ws_size,
                              hipStream_t stream) {
    const float* x  = (const float*)d_in[0];
    const int*   ei = (const int*)d_in[1];
    const float* W1 = (const float*)d_in[2];
    const float* b1 = (const float*)d_in[3];
    const float* W2 = (const float*)d_in[4];
    const float* b2 = (const float*)d_in[5];
    const float* gw = (const float*)d_in[6];
    const float* gb = (const float*)d_in[7];
    float* out = (float*)d_out;

    // ws layout (floats): [degi N][cnti N][srow E][snde E][nd N][invcnt N][y N][z N][y2 N][z2 N]
    //                     [ha N*H][hb N*H][off N+1][bsum SCAN_BLOCKS]
    // rankc aliases hb (dead before agg1 writes hb). total ~33.8 MB
    int*   degi   = (int*)d_ws;
    int*   cnti   = degi + N_NODES;
    int*   srow   = cnti + N_NODES;
    float* snde   = (float*)(srow + N_EDGES);
    float* nd     = snde + N_EDGES;
    float* invcnt = nd + N_NODES;
    float* y      = invcnt + N_NODES;
    float* z      = y + N_NODES;
    float* y2     = z + N_NODES;
    float* z2     = y2 + N_NODES;
    float* ha     = z2 + N_NODES;
    float* hb     = ha + (size_t)N_NODES * HID;
    int*   off    = (int*)(hb + (size_t)N_NODES * HID);
    int*   bsum   = off + N_NODES + 1;
    int*   rankc  = (int*)hb;  // E ints <= N*H floats, dead before agg1 writes hb

    const int* row = ei;
    const int* col = ei + N_EDGES;

    hipMemsetAsync(degi, 0, (size_t)2 * N_NODES * sizeof(int), stream);

    degree_kernel<<<N_EDGES / 256, 256, 0, stream>>>(row, col, degi, cnti, rankc);
    nd_kernel<<<SCAN_BLOCKS, 256, 0, stream>>>(degi, cnti, nd, invcnt);
    scan1_kernel<<<SCAN_BLOCKS, 256, 0, stream>>>(cnti, off, bsum);
    scan2_kernel<<<1, 256, 0, stream>>>(bsum);
    scan3_kernel<<<SCAN_BLOCKS, 256, 0, stream>>>(off, bsum);
    scatter_kernel<<<N_EDGES / 256, 256, 0, stream>>>(row, col, rankc, off, nd, srow, snde);
    proj_kernel<<<(N_NODES + 63) / 64, 256, 0, stream>>>(x, W1, b1, ha);
    yz_kernel<<<N_NODES / 4, 256, 0, stream>>>(ha, gw, y, z);

    agg1_kernel<<<N_NODES / 4, 256, 0, stream>>>(ha, srow, snde, off, invcnt, y, z, gb,
                                                 gw + 2 * HID, hb, y2, z2);
    agg2_kernel<<<N_NODES / 4, 256, 0, stream>>>(hb, ha, srow, snde, off, invcnt, y2, z2,
                                                 gb + 1, W2, b2, out);
}

// Round 6
// 326.704 us; speedup vs baseline: 18.3239x; 1.0731x over previous
//
#include <hip/hip_runtime.h>
#include <math.h>

#define N_NODES 50000
#define N_EDGES 800000
#define NFEAT 256
#define HID 64
#define NCLS 40
#define EPS_RES 0.3f
#define ROWSZ 68  // LDS row pitch for proj (64 + 4 pad)
#define SCAN_BLOCKS ((N_NODES + 255) / 256)  // 196

typedef unsigned int uint;
typedef unsigned short ushort;

__device__ __forceinline__ float bflo(uint u) { return __uint_as_float(u << 16); }
__device__ __forceinline__ float bfhi(uint u) { return __uint_as_float(u & 0xFFFF0000u); }
__device__ __forceinline__ uint bf16rne(float f) {
    uint u = __float_as_uint(f);
    return (u + 0x7FFFu + ((u >> 16) & 1u)) >> 16;
}
__device__ __forceinline__ uint bf16rne2(float a, float b) {
    return bf16rne(a) | (bf16rne(b) << 16);
}

// ---------------- degree + per-edge rank ----------------
// At the measured atomic ceiling (~19 ops/ns, ~32B EA write per op): 1.6M ops ~= 84us floor.
__global__ void degree_kernel(const int* __restrict__ row, const int* __restrict__ col,
                              int* __restrict__ degi, int* __restrict__ cnti,
                              int* __restrict__ rankc) {
    int e = blockIdx.x * 256 + threadIdx.x;
    atomicAdd(&degi[row[e]], 1);
    rankc[e] = atomicAdd(&cnti[col[e]], 1);
}

// ---------------- 3-phase grid-wide exclusive scan of cnti -> off (+ fused nd/invcnt) ----
__device__ __forceinline__ int block_excl_scan_256(int v, int t, int* wsum) {
    int lane = t & 63, w = t >> 6;
    int sv = v;
#pragma unroll
    for (int d = 1; d < 64; d <<= 1) {
        int o = __shfl_up(sv, d);
        if (lane >= d) sv += o;
    }
    if (lane == 63) wsum[w] = sv;
    __syncthreads();
    int add = 0;
    for (int i = 0; i < w; i++) add += wsum[i];
    return sv + add - v;
}

__global__ void scan1_kernel(const int* __restrict__ cnti, const int* __restrict__ degi,
                             int* __restrict__ off, int* __restrict__ bsum,
                             float* __restrict__ nd, float* __restrict__ invcnt) {
    __shared__ int wsum[4];
    int t = threadIdx.x;
    int idx = blockIdx.x * 256 + t;
    int v = (idx < N_NODES) ? cnti[idx] : 0;
    if (idx < N_NODES) {
        int d = degi[idx]; if (d < 1) d = 1;
        nd[idx] = rsqrtf((float)d);
        int c = v; if (c < 1) c = 1;
        invcnt[idx] = 1.0f / (float)c;
    }
    int excl = block_excl_scan_256(v, t, wsum);
    if (idx < N_NODES) off[idx] = excl;
    if (t == 255) bsum[blockIdx.x] = excl + v;
}

__global__ void scan2_kernel(int* __restrict__ bsum) {
    __shared__ int wsum[4];
    int t = threadIdx.x;
    int v = (t < SCAN_BLOCKS) ? bsum[t] : 0;
    int excl = block_excl_scan_256(v, t, wsum);
    if (t < SCAN_BLOCKS) bsum[t] = excl;
}

__global__ void scan3_kernel(int* __restrict__ off, const int* __restrict__ bsum) {
    int t = threadIdx.x;
    int idx = blockIdx.x * 256 + t;
    if (idx < N_NODES) off[idx] += bsum[blockIdx.x];
    if (idx == 0) off[N_NODES] = N_EDGES;
}

// ---------------- CSR scatter: one 8B store per edge {src, nd[r]*nd[c]} ----------------
__global__ void scatter_kernel(const int* __restrict__ row, const int* __restrict__ col,
                               const int* __restrict__ rankc, const int* __restrict__ off,
                               const float* __restrict__ nd, int2* __restrict__ sedge) {
    int e = blockIdx.x * 256 + threadIdx.x;
    int r = row[e], c = col[e];
    int p = off[c] + rankc[e];
    int2 se;
    se.x = r;
    se.y = __float_as_int(nd[r] * nd[c]);
    sedge[p] = se;
}

// ---------------- input projection: ha(fp32) + habf(bf16) = relu(x @ W1^T + b1) ----------
__global__ __launch_bounds__(256) void proj_kernel(const float* __restrict__ x,
                                                   const float* __restrict__ W1,
                                                   const float* __restrict__ b1,
                                                   float* __restrict__ ha,
                                                   ushort* __restrict__ habf) {
    __shared__ float xs[64 * ROWSZ];
    __shared__ float ws[64 * ROWSZ];
    int t = threadIdx.x;
    int nb = blockIdx.x * 64;
    int lane = t & 63, w = t >> 6;
    int l15 = lane & 15, g = lane >> 4;
    int hbase = 16 * w + 4 * g;
    float acc[4][4];
#pragma unroll
    for (int j = 0; j < 4; j++)
#pragma unroll
        for (int i = 0; i < 4; i++) acc[j][i] = 0.f;

    for (int kc = 0; kc < NFEAT; kc += 64) {
        __syncthreads();
#pragma unroll
        for (int i = 0; i < 4; i++) {
            int idx = t + 256 * i;
            int r_ = idx >> 4;
            int kq = idx & 15;
            int gn = nb + r_;
            float4 v = make_float4(0.f, 0.f, 0.f, 0.f);
            if (gn < N_NODES) v = *(const float4*)(x + (size_t)gn * NFEAT + kc + kq * 4);
            *(float4*)(xs + r_ * ROWSZ + kq * 4) = v;
            float4 wv = *(const float4*)(W1 + (size_t)r_ * NFEAT + kc + kq * 4);
            *(float4*)(ws + r_ * ROWSZ + kq * 4) = wv;
        }
        __syncthreads();
#pragma unroll 4
        for (int k = 0; k < 64; k += 4) {
            float4 a[4], b[4];
#pragma unroll
            for (int j = 0; j < 4; j++) a[j] = *(const float4*)(xs + (l15 + 16 * j) * ROWSZ + k);
#pragma unroll
            for (int i = 0; i < 4; i++) b[i] = *(const float4*)(ws + (hbase + i) * ROWSZ + k);
#pragma unroll
            for (int j = 0; j < 4; j++)
#pragma unroll
                for (int i = 0; i < 4; i++)
                    acc[j][i] += a[j].x * b[i].x + a[j].y * b[i].y + a[j].z * b[i].z + a[j].w * b[i].w;
        }
    }
    float4 bias = *(const float4*)(b1 + hbase);
#pragma unroll
    for (int j = 0; j < 4; j++) {
        int gn = nb + l15 + 16 * j;
        if (gn < N_NODES) {
            float4 o;
            o.x = fmaxf(acc[j][0] + bias.x, 0.f);
            o.y = fmaxf(acc[j][1] + bias.y, 0.f);
            o.z = fmaxf(acc[j][2] + bias.z, 0.f);
            o.w = fmaxf(acc[j][3] + bias.w, 0.f);
            *(float4*)(ha + (size_t)gn * HID + hbase) = o;
            uint2 pk;
            pk.x = bf16rne2(o.x, o.y);
            pk.y = bf16rne2(o.z, o.w);
            *(uint2*)(habf + (size_t)gn * HID + hbase) = pk;
        }
    }
}

// ---------------- per-node gate projections: y = h.wa, z = h.wb ----------------
__global__ void yz_kernel(const float* __restrict__ h, const float* __restrict__ gw,
                          float* __restrict__ y, float* __restrict__ z) {
    int t = threadIdx.x;
    int lane = t & 63;
    int node = blockIdx.x * 4 + (t >> 6);
    float wa = gw[lane], wb = gw[HID + lane];
    float v = h[node * HID + lane];
    float p = v * wa, q = v * wb;
#pragma unroll
    for (int s = 1; s < 64; s <<= 1) { p += __shfl_xor(p, s); q += __shfl_xor(q, s); }
    if (lane == 0) { y[node] = p; z[node] = q; }
}

// ---------------- CSR aggregation core: 8 edges/iter, bf16 gathers, fused gate ----------
// lane group q=lane>>3 owns edge slot q; each lane holds 8 channels c8..c8+7.
__device__ __forceinline__ void agg_core8(const ushort* __restrict__ hbf,
                                          const int2* __restrict__ sedge,
                                          const float* __restrict__ y,
                                          float zc_b, int e0, int e1, int q, int c8,
                                          float acc[8], float& gs_out) {
#pragma unroll
    for (int i = 0; i < 8; i++) acc[i] = 0.f;
    float gs = 0.f;
    if (e0 < e1) {
        int e = e0 + q;
        int ec = (e < e1) ? e : e0;
        int2 se = sedge[ec];
        int r_n = se.x;
        float nde_n = (e < e1) ? __int_as_float(se.y) : 0.f;
        float y_n = y[r_n];
        uint4 u_n = *(const uint4*)(hbf + (size_t)r_n * HID + c8);
        for (int base = e0; base < e1; base += 8) {
            int e2 = base + 8 + q;
            int ec2 = (e2 < e1) ? e2 : e0;
            int2 se2 = sedge[ec2];
            float nde2 = (e2 < e1) ? __int_as_float(se2.y) : 0.f;
            float y2v = y[se2.x];
            uint4 u2 = *(const uint4*)(hbf + (size_t)se2.x * HID + c8);
            float g = tanhf(y_n + zc_b) * nde_n;
            acc[0] += g * bflo(u_n.x);
            acc[1] += g * bfhi(u_n.x);
            acc[2] += g * bflo(u_n.y);
            acc[3] += g * bfhi(u_n.y);
            acc[4] += g * bflo(u_n.z);
            acc[5] += g * bfhi(u_n.z);
            acc[6] += g * bflo(u_n.w);
            acc[7] += g * bfhi(u_n.w);
            gs += g;
            nde_n = nde2; y_n = y2v; u_n = u2;
        }
    }
#pragma unroll
    for (int s = 8; s < 64; s <<= 1) {
#pragma unroll
        for (int i = 0; i < 8; i++) acc[i] += __shfl_xor(acc[i], s);
        gs += __shfl_xor(gs, s);
    }
    gs_out = gs;
}

// ---------------- layer 1 agg + fused y2/z2; writes bf16 hbbf only ----------------
__global__ void agg1_kernel(const float* __restrict__ ha, const ushort* __restrict__ habf,
                            const int2* __restrict__ sedge, const int* __restrict__ off,
                            const float* __restrict__ invcnt, const float* __restrict__ y,
                            const float* __restrict__ z, const float* __restrict__ gb,
                            const float* __restrict__ gw2, ushort* __restrict__ hbbf,
                            float* __restrict__ y2, float* __restrict__ z2) {
    int t = threadIdx.x;
    int lane = t & 63;
    int node = blockIdx.x * 4 + (t >> 6);
    int q = lane >> 3, c8 = (lane & 7) * 8;
    float4 ra = *(const float4*)(ha + (size_t)node * HID + c8);
    float4 rb = *(const float4*)(ha + (size_t)node * HID + c8 + 4);
    float raw8[8] = {ra.x, ra.y, ra.z, ra.w, rb.x, rb.y, rb.z, rb.w};
    float zc_b = z[node] + gb[0];
    float acc[8]; float gs;
    agg_core8(habf, sedge, y, zc_b, off[node], off[node + 1], q, c8, acc, gs);
    float invc = invcnt[node];
    float o[8];
#pragma unroll
    for (int i = 0; i < 8; i++) o[i] = EPS_RES * raw8[i] + (acc[i] + gs * raw8[i]) * invc;
    if (q == 0) {
        uint4 pk;
        pk.x = bf16rne2(o[0], o[1]);
        pk.y = bf16rne2(o[2], o[3]);
        pk.z = bf16rne2(o[4], o[5]);
        pk.w = bf16rne2(o[6], o[7]);
        *(uint4*)(hbbf + (size_t)node * HID + c8) = pk;
    }
    // fused layer-2 gate projections (every 8-lane group holds identical o)
    float4 wa0 = *(const float4*)(gw2 + c8);
    float4 wa1 = *(const float4*)(gw2 + c8 + 4);
    float4 wb0 = *(const float4*)(gw2 + HID + c8);
    float4 wb1 = *(const float4*)(gw2 + HID + c8 + 4);
    float p = o[0] * wa0.x + o[1] * wa0.y + o[2] * wa0.z + o[3] * wa0.w
            + o[4] * wa1.x + o[5] * wa1.y + o[6] * wa1.z + o[7] * wa1.w;
    float qq = o[0] * wb0.x + o[1] * wb0.y + o[2] * wb0.z + o[3] * wb0.w
             + o[4] * wb1.x + o[5] * wb1.y + o[6] * wb1.z + o[7] * wb1.w;
#pragma unroll
    for (int s = 1; s < 8; s <<= 1) { p += __shfl_xor(p, s); qq += __shfl_xor(qq, s); }
    if (lane == 0) { y2[node] = p; z2[node] = qq; }
}

// ---------------- layer 2 agg + classifier + log_softmax ----------------
__global__ void agg2_kernel(const ushort* __restrict__ hbbf, const float* __restrict__ ha,
                            const int2* __restrict__ sedge, const int* __restrict__ off,
                            const float* __restrict__ invcnt, const float* __restrict__ y2,
                            const float* __restrict__ z2, const float* __restrict__ gb,
                            const float* __restrict__ W2, const float* __restrict__ b2,
                            float* __restrict__ out) {
    __shared__ float w2s[NCLS * 65];
    __shared__ float b2s[NCLS];
    __shared__ float hs[4 * HID];
    int t = threadIdx.x;
    for (int i = t; i < NCLS * HID; i += 256) w2s[(i >> 6) * 65 + (i & 63)] = W2[i];
    if (t < NCLS) b2s[t] = b2[t];
    int lane = t & 63;
    int wv = t >> 6;
    int node = blockIdx.x * 4 + wv;
    int q = lane >> 3, c8 = (lane & 7) * 8;
    uint4 hc = *(const uint4*)(hbbf + (size_t)node * HID + c8);
    float hcv[8] = {bflo(hc.x), bfhi(hc.x), bflo(hc.y), bfhi(hc.y),
                    bflo(hc.z), bfhi(hc.z), bflo(hc.w), bfhi(hc.w)};
    float4 ra = *(const float4*)(ha + (size_t)node * HID + c8);
    float4 rb = *(const float4*)(ha + (size_t)node * HID + c8 + 4);
    float raw8[8] = {ra.x, ra.y, ra.z, ra.w, rb.x, rb.y, rb.z, rb.w};
    float zc_b = z2[node] + gb[0];
    float acc[8]; float gs;
    agg_core8(hbbf, sedge, y2, zc_b, off[node], off[node + 1], q, c8, acc, gs);
    float invc = invcnt[node];
    if (q == 0) {
        float4 o0, o1;
        o0.x = EPS_RES * raw8[0] + (acc[0] + gs * hcv[0]) * invc;
        o0.y = EPS_RES * raw8[1] + (acc[1] + gs * hcv[1]) * invc;
        o0.z = EPS_RES * raw8[2] + (acc[2] + gs * hcv[2]) * invc;
        o0.w = EPS_RES * raw8[3] + (acc[3] + gs * hcv[3]) * invc;
        o1.x = EPS_RES * raw8[4] + (acc[4] + gs * hcv[4]) * invc;
        o1.y = EPS_RES * raw8[5] + (acc[5] + gs * hcv[5]) * invc;
        o1.z = EPS_RES * raw8[6] + (acc[6] + gs * hcv[6]) * invc;
        o1.w = EPS_RES * raw8[7] + (acc[7] + gs * hcv[7]) * invc;
        *(float4*)(hs + wv * HID + c8) = o0;
        *(float4*)(hs + wv * HID + c8 + 4) = o1;
    }
    __syncthreads();
    float logit = 0.f;
    if (lane < NCLS) {
        const float* wr = w2s + lane * 65;
        const float* hrow = hs + wv * HID;
#pragma unroll
        for (int k = 0; k < HID; k++) logit += hrow[k] * wr[k];
        logit += b2s[lane];
    }
    float v = (lane < NCLS) ? logit : -INFINITY;
#pragma unroll
    for (int s = 1; s < 64; s <<= 1) v = fmaxf(v, __shfl_xor(v, s));
    float ex = (lane < NCLS) ? expf(logit - v) : 0.f;
#pragma unroll
    for (int s = 1; s < 64; s <<= 1) ex += __shfl_xor(ex, s);
    float ls = v + logf(ex);
    if (lane < NCLS) out[node * NCLS + lane] = logit - ls;
}

extern "C" void kernel_launch(void* const* d_in, const int* in_sizes, int n_in,
                              void* d_out, int out_size, void* d_ws, size_t ws_size,
                              hipStream_t stream) {
    const float* x  = (const float*)d_in[0];
    const int*   ei = (const int*)d_in[1];
    const float* W1 = (const float*)d_in[2];
    const float* b1 = (const float*)d_in[3];
    const float* W2 = (const float*)d_in[4];
    const float* b2 = (const float*)d_in[5];
    const float* gw = (const float*)d_in[6];
    const float* gb = (const float*)d_in[7];
    float* out = (float*)d_out;

    // ws layout (4B words): [degi N][cnti N][sedge 2E][nd N][invcnt N][y N][z N][y2 N][z2 N]
    //   [ha 64N][habf 32N][hbbf 32N][off N+1][bsum 196]
    // rankc aliases habf (written by degree, consumed by scatter, before proj writes habf).
    // total ~= 8.45M words = 33.8 MB
    int*   degi   = (int*)d_ws;
    int*   cnti   = degi + N_NODES;
    int2*  sedge  = (int2*)(cnti + N_NODES);
    float* nd     = (float*)(sedge + N_EDGES);
    float* invcnt = nd + N_NODES;
    float* y      = invcnt + N_NODES;
    float* z      = y + N_NODES;
    float* y2     = z + N_NODES;
    float* z2     = y2 + N_NODES;
    float* ha     = z2 + N_NODES;
    ushort* habf  = (ushort*)(ha + (size_t)N_NODES * HID);
    ushort* hbbf  = habf + (size_t)N_NODES * HID;
    int*   off    = (int*)(hbbf + (size_t)N_NODES * HID);
    int*   bsum   = off + N_NODES + 1;
    int*   rankc  = (int*)habf;  // E ints <= 32N words, dead before proj writes habf

    const int* row = ei;
    const int* col = ei + N_EDGES;

    hipMemsetAsync(degi, 0, (size_t)2 * N_NODES * sizeof(int), stream);

    degree_kernel<<<N_EDGES / 256, 256, 0, stream>>>(row, col, degi, cnti, rankc);
    scan1_kernel<<<SCAN_BLOCKS, 256, 0, stream>>>(cnti, degi, off, bsum, nd, invcnt);
    scan2_kernel<<<1, 256, 0, stream>>>(bsum);
    scan3_kernel<<<SCAN_BLOCKS, 256, 0, stream>>>(off, bsum);
    scatter_kernel<<<N_EDGES / 256, 256, 0, stream>>>(row, col, rankc, off, nd, sedge);
    proj_kernel<<<(N_NODES + 63) / 64, 256, 0, stream>>>(x, W1, b1, ha, habf);
    yz_kernel<<<N_NODES / 4, 256, 0, stream>>>(ha, gw, y, z);

    agg1_kernel<<<N_NODES / 4, 256, 0, stream>>>(ha, habf, sedge, off, invcnt, y, z, gb,
                                                 gw + 2 * HID, hbbf, y2, z2);
    agg2_kernel<<<N_NODES / 4, 256, 0, stream>>>(hbbf, ha, sedge, off, invcnt, y2, z2,
                                                 gb + 1, W2, b2, out);
}